// Round 2
// baseline (808.141 us; speedup 1.0000x reference)
//
#include <hip/hip_runtime.h>
#include <hip/hip_bf16.h>

typedef float float4v __attribute__((ext_vector_type(4)));

__device__ __forceinline__ float sigm(float x) { return 1.0f / (1.0f + __expf(-x)); }

// ---------------------------------------------------------------------------
// h0 = relu(nodes @ W_en + b_en)   [4,64,32]@[32,64] -> [4,64,64]
__global__ void k_encode(const float* __restrict__ nodes, const float* __restrict__ W_en,
                         const float* __restrict__ b_en, float* __restrict__ h)
{
    int idx = blockIdx.x * 256 + threadIdx.x;   // 16384 = B*N*D
    int d = idx & 63, bn = idx >> 6;
    const float* np_ = nodes + bn * 32;
    float acc = b_en[d];
#pragma unroll
    for (int k = 0; k < 32; ++k)
        acc = fmaf(np_[k], W_en[k * 64 + d], acc);
    h[idx] = fmaxf(acc, 0.f);
}

// ---------------------------------------------------------------------------
// One message-passing iteration, fully fused per receiver row (b,i):
//   agg[b,i,:] = sum_{j active} relu(edges[b,i*64+j] @ W_agg + b_agg).reshape(64,64) @ h[b,j]
//   h1 = GRU(h_row, 0); h_next_row = GRU(agg_row, h1)
// grid = 256 blocks (b*64+i), block = 256 threads (4 waves; wave jq handles
// senders j in [jq*16, jq*16+16); lane d owns output dim d).
__global__ __launch_bounds__(256) void k_step(
    const float* __restrict__ edges, const float* __restrict__ W_agg, const float* __restrict__ b_agg,
    const float* __restrict__ W_ih, const float* __restrict__ W_hh,
    const float* __restrict__ b_ih, const float* __restrict__ b_hh,
    const float* __restrict__ h_cur, float* __restrict__ h_next)
{
    __shared__ float h_s[64][64];   // h for this batch, 16 KB
    __shared__ float red[4][64];
    __shared__ float aggS[64];
    __shared__ float g1[192];
    __shared__ float h1S[64];
    __shared__ float g2i[192];
    __shared__ float g2h[192];

    int tid = threadIdx.x;
    int b = blockIdx.x >> 6, i = blockIdx.x & 63;
    int d = tid & 63, jq = tid >> 6;

    // stage h[b] into LDS (coalesced float4)
    const float* hb = h_cur + b * 4096;
    float* hflat = &h_s[0][0];
#pragma unroll
    for (int r = 0; r < 4; ++r) {
        int off = (r * 256 + tid) * 4;
        *(float4v*)(hflat + off) = *(const float4v*)(hb + off);
    }
    __syncthreads();

    // fused A-recompute + matvec + aggregate (skip masked edges)
    float acc = 0.f;
    const float* bagg_d = b_agg + d * 64;
    const float* wagg_d = W_agg + d * 64;
    for (int j = jq * 16; j < jq * 16 + 16; ++j) {
        const float* ep = edges + ((size_t)(b * 4096 + i * 64 + j)) * 16;
        if (ep[0] == 0.0f) continue;        // bond indicator == 0 -> masked out
        float ev[16];
#pragma unroll
        for (int u = 0; u < 16; u += 4) {
            float4v e4 = *(const float4v*)(ep + u);
            ev[u] = e4[0]; ev[u + 1] = e4[1]; ev[u + 2] = e4[2]; ev[u + 3] = e4[3];
        }
#pragma unroll
        for (int jc = 0; jc < 8; ++jc) {
            float w[8];
            *(float4v*)(w)     = *(const float4v*)(bagg_d + jc * 8);
            *(float4v*)(w + 4) = *(const float4v*)(bagg_d + jc * 8 + 4);
#pragma unroll
            for (int k = 0; k < 16; ++k) {
                const float* ap = wagg_d + k * 4096 + jc * 8;
                float4v a0 = *(const float4v*)ap;
                float4v a1 = *(const float4v*)(ap + 4);
                w[0] = fmaf(ev[k], a0[0], w[0]);
                w[1] = fmaf(ev[k], a0[1], w[1]);
                w[2] = fmaf(ev[k], a0[2], w[2]);
                w[3] = fmaf(ev[k], a0[3], w[3]);
                w[4] = fmaf(ev[k], a1[0], w[4]);
                w[5] = fmaf(ev[k], a1[1], w[5]);
                w[6] = fmaf(ev[k], a1[2], w[6]);
                w[7] = fmaf(ev[k], a1[3], w[7]);
            }
#pragma unroll
            for (int u = 0; u < 8; ++u)
                acc = fmaf(fmaxf(w[u], 0.f), h_s[j][jc * 8 + u], acc);
        }
    }
    red[jq][d] = acc;
    __syncthreads();

    // reduce 4 wave-partials -> agg row; concurrently compute gi of GRU cell 1
    if (tid < 64) aggS[tid] = red[0][tid] + red[1][tid] + red[2][tid] + red[3][tid];
    if (tid < 192) {
        float g = b_ih[tid];
        const float* wr = W_ih + tid * 64;
#pragma unroll
        for (int k = 0; k < 64; ++k) g = fmaf(h_s[i][k], wr[k], g);
        g1[tid] = g;
    }
    __syncthreads();
    // cell 1 with h_prev = 0:  gh = b_hh
    if (tid < 64) {
        float r1 = sigm(g1[tid] + b_hh[tid]);
        float z1 = sigm(g1[64 + tid] + b_hh[64 + tid]);
        float n1 = tanhf(g1[128 + tid] + r1 * b_hh[128 + tid]);
        h1S[tid] = (1.f - z1) * n1;
    }
    __syncthreads();
    // cell 2: x = agg, h = h1
    if (tid < 192) {
        float gi = b_ih[tid];
        float gh = b_hh[tid];
        const float* wri = W_ih + tid * 64;
        const float* wrh = W_hh + tid * 64;
#pragma unroll
        for (int k = 0; k < 64; ++k) {
            gi = fmaf(aggS[k], wri[k], gi);
            gh = fmaf(h1S[k], wrh[k], gh);
        }
        g2i[tid] = gi; g2h[tid] = gh;
    }
    __syncthreads();
    if (tid < 64) {
        float r = sigm(g2i[tid] + g2h[tid]);
        float z = sigm(g2i[64 + tid] + g2h[64 + tid]);
        float n = tanhf(g2i[128 + tid] + r * g2h[128 + tid]);
        float hn = (1.f - z) * n + z * h1S[tid];
        h_next[(b * 64 + i) * 64 + tid] = hn;
    }
}

// ---------------------------------------------------------------------------
// Readout: per pair p: cat = [h_i(64), edges(16), h_j(64)];
// out = relu(relu(cat@W_r1)@W_r2)@W_r3 + b_r3.   4 pairs per 128-thread block.
__global__ __launch_bounds__(128) void k_readout(
    const float* __restrict__ edges, const float* __restrict__ h,
    const float* __restrict__ W_r1, const float* __restrict__ b_r1,
    const float* __restrict__ W_r2, const float* __restrict__ b_r2,
    const float* __restrict__ W_r3, const float* __restrict__ b_r3,
    float* __restrict__ out)
{
    __shared__ float cat[4][144];
    __shared__ float a1[4][128];
    __shared__ float rbuf[4][128];
    int t = threadIdx.x;
    int p0 = blockIdx.x * 4;

    for (int idx = t; idx < 4 * 144; idx += 128) {
        int u = idx / 144, c = idx - u * 144;
        int p = p0 + u, b = p >> 12, e = p & 4095, ii = e >> 6, jj = e & 63;
        float v;
        if (c < 64)      v = h[(b * 64 + ii) * 64 + c];
        else if (c < 80) v = edges[(size_t)p * 16 + (c - 64)];
        else             v = h[(b * 64 + jj) * 64 + (c - 80)];
        cat[u][c] = v;
    }
    __syncthreads();

    float s[4];
    float bb = b_r1[t];
    s[0] = s[1] = s[2] = s[3] = bb;
    for (int k = 0; k < 144; ++k) {
        float w = W_r1[k * 128 + t];
#pragma unroll
        for (int u = 0; u < 4; ++u) s[u] = fmaf(cat[u][k], w, s[u]);
    }
#pragma unroll
    for (int u = 0; u < 4; ++u) a1[u][t] = fmaxf(s[u], 0.f);
    __syncthreads();

    float bb2 = b_r2[t];
    float s2[4];
    s2[0] = s2[1] = s2[2] = s2[3] = bb2;
    for (int k = 0; k < 128; ++k) {
        float w = W_r2[k * 128 + t];
#pragma unroll
        for (int u = 0; u < 4; ++u) s2[u] = fmaf(a1[u][k], w, s2[u]);
    }
    float w3 = W_r3[t];
#pragma unroll
    for (int u = 0; u < 4; ++u) rbuf[u][t] = fmaxf(s2[u], 0.f) * w3;
    __syncthreads();

    if (t < 4) {
        float accv = b_r3[0];
        for (int k = 0; k < 128; ++k) accv += rbuf[t][k];
        out[p0 + t] = accv;
    }
}

// ---------------------------------------------------------------------------
extern "C" void kernel_launch(void* const* d_in, const int* in_sizes, int n_in,
                              void* d_out, int out_size, void* d_ws, size_t ws_size,
                              hipStream_t stream)
{
    const float* edges = (const float*)d_in[0];
    const float* nodes = (const float*)d_in[1];
    // d_in[2] adjacency: unused
    const float* W_en  = (const float*)d_in[3];
    const float* b_en  = (const float*)d_in[4];
    const float* W_agg = (const float*)d_in[5];
    const float* b_agg = (const float*)d_in[6];
    const float* W_ih  = (const float*)d_in[7];
    const float* W_hh  = (const float*)d_in[8];
    const float* b_ih  = (const float*)d_in[9];
    const float* b_hh  = (const float*)d_in[10];
    const float* W_r1  = (const float*)d_in[11];
    const float* b_r1  = (const float*)d_in[12];
    const float* W_r2  = (const float*)d_in[13];
    const float* b_r2  = (const float*)d_in[14];
    const float* W_r3  = (const float*)d_in[15];
    const float* b_r3  = (const float*)d_in[16];

    float* hA = (float*)d_ws;            // [4,64,64]
    float* hB = hA + 4 * 64 * 64;        // [4,64,64]  (ping-pong)

    k_encode<<<64, 256, 0, stream>>>(nodes, W_en, b_en, hA);
    k_step<<<256, 256, 0, stream>>>(edges, W_agg, b_agg, W_ih, W_hh, b_ih, b_hh, hA, hB);
    k_step<<<256, 256, 0, stream>>>(edges, W_agg, b_agg, W_ih, W_hh, b_ih, b_hh, hB, hA);
    k_step<<<256, 256, 0, stream>>>(edges, W_agg, b_agg, W_ih, W_hh, b_ih, b_hh, hA, hB);
    k_readout<<<4096, 128, 0, stream>>>(edges, hB, W_r1, b_r1, W_r2, b_r2, W_r3, b_r3,
                                        (float*)d_out);
}

// Round 3
// 272.381 us; speedup vs baseline: 2.9669x; 2.9669x over previous
//
#include <hip/hip_runtime.h>

typedef float float4v __attribute__((ext_vector_type(4)));

__device__ __forceinline__ float sigm(float x) { return 1.0f / (1.0f + __expf(-x)); }

// ---------------------------------------------------------------------------
// h0 = relu(nodes @ W_en + b_en)   [4,64,32]@[32,64] -> [4,64,64]
__global__ void k_encode(const float* __restrict__ nodes, const float* __restrict__ W_en,
                         const float* __restrict__ b_en, float* __restrict__ h)
{
    int idx = blockIdx.x * 256 + threadIdx.x;   // 16384 = B*N*D
    int d = idx & 63, bn = idx >> 6;
    const float* np_ = nodes + bn * 32;
    float acc = b_en[d];
#pragma unroll
    for (int k = 0; k < 32; ++k)
        acc = fmaf(np_[k], W_en[k * 64 + d], acc);
    h[idx] = fmaxf(acc, 0.f);
}

// ---------------------------------------------------------------------------
// Compact the active-edge list (mask is constant across iterations).
// list order is nondeterministic (atomic bases) but downstream output is
// invariant: msgs are indexed by global edge id, aggregation is in fixed order.
__global__ void k_prep(const float* __restrict__ edges, int* __restrict__ cnt,
                       int* __restrict__ list)
{
    int e = blockIdx.x * 256 + threadIdx.x;     // 64 blocks cover 16384 edges
    bool act = edges[(size_t)e * 16] != 0.f;
    unsigned long long m = __ballot(act);
    int lane = threadIdx.x & 63;
    int base = 0;
    if (lane == 0) base = atomicAdd(cnt, __popcll(m));
    base = __shfl(base, 0, 64);
    if (act) {
        int pos = __popcll(m & ((1ull << lane) - 1ull));
        list[base + pos] = e;
    }
}

// ---------------------------------------------------------------------------
// Per-iteration messages for ACTIVE edges only:
//   msg[e,:] = relu(edges[e] @ W_agg + b_agg).reshape(64,64) @ h[b_e, j_e]
// Tile = 32 edges per block, 256 threads: s = t&31 edge slot, q = t>>5 (8 i's
// per column chunk, one i per q). W_agg staged through LDS in 8 chunks of
// 512 columns; every LDS read in the inner loop is wave-broadcast.
__global__ __launch_bounds__(256) void k_amsg(
    const float* __restrict__ edges, const float* __restrict__ W_agg,
    const float* __restrict__ b_agg, const float* __restrict__ h_cur,
    const int* __restrict__ cnt, const int* __restrict__ list,
    float* __restrict__ msgs)
{
    __shared__ float Ws[16][512];   // 32 KB chunk of W_agg
    __shared__ float bs[512];

    int nact = cnt[0];
    int tile0 = blockIdx.x * 32;
    if (tile0 >= nact) return;      // whole block exits together (pre-sync)
    int nE = min(32, nact - tile0);

    int t = threadIdx.x;
    int s = t & 31, q = t >> 5;
    int e = list[tile0 + (s < nE ? s : 0)];
    int b = e >> 12, j = e & 63;

    // edge features -> 16 regs (row is 64B, lane-contiguous loads)
    float Er[16];
    {
        const float* ep = edges + (size_t)e * 16;
#pragma unroll
        for (int u = 0; u < 16; u += 4) {
            float4v v = *(const float4v*)(ep + u);
            Er[u] = v[0]; Er[u + 1] = v[1]; Er[u + 2] = v[2]; Er[u + 3] = v[3];
        }
    }
    // sender state h_j -> 64 regs
    float hr[64];
    {
        const float* hp = h_cur + ((b << 6) + j) * 64;
#pragma unroll
        for (int u = 0; u < 64; u += 4) {
            float4v v = *(const float4v*)(hp + u);
            hr[u] = v[0]; hr[u + 1] = v[1]; hr[u + 2] = v[2]; hr[u + 3] = v[3];
        }
    }

    for (int ic = 0; ic < 8; ++ic) {
        __syncthreads();            // previous chunk fully consumed
        {   // stage Ws[16][512] = W_agg[:, ic*512 .. +512), coalesced
            int kr = t >> 4, seg = t & 15;
            const float* gp = W_agg + kr * 4096 + ic * 512 + seg * 32;
            float* lp = &Ws[kr][seg * 32];
#pragma unroll
            for (int u = 0; u < 32; u += 4)
                *(float4v*)(lp + u) = *(const float4v*)(gp + u);
            if (t < 128)
                *(float4v*)(bs + t * 4) = *(const float4v*)(b_agg + ic * 512 + t * 4);
        }
        __syncthreads();

        // this thread's output dim: i = ic*8 + q ; local cols = q*64 + jj
        float msum = 0.f;
#pragma unroll
        for (int jj = 0; jj < 64; jj += 4) {
            float4v a = *(const float4v*)(bs + q * 64 + jj);
#pragma unroll
            for (int k = 0; k < 16; ++k) {
                float4v w = *(const float4v*)(&Ws[k][q * 64 + jj]);   // broadcast
                a[0] = fmaf(Er[k], w[0], a[0]);
                a[1] = fmaf(Er[k], w[1], a[1]);
                a[2] = fmaf(Er[k], w[2], a[2]);
                a[3] = fmaf(Er[k], w[3], a[3]);
            }
            msum = fmaf(fmaxf(a[0], 0.f), hr[jj],     msum);
            msum = fmaf(fmaxf(a[1], 0.f), hr[jj + 1], msum);
            msum = fmaf(fmaxf(a[2], 0.f), hr[jj + 2], msum);
            msum = fmaf(fmaxf(a[3], 0.f), hr[jj + 3], msum);
        }
        if (s < nE) msgs[(size_t)e * 64 + ic * 8 + q] = msum;
    }
}

// ---------------------------------------------------------------------------
// Masked aggregation over senders + fused 2-cell GRU. 256 blocks = (b,i) rows.
__global__ __launch_bounds__(256) void k_agg_gru(
    const float* __restrict__ edges, const float* __restrict__ msgs,
    const float* __restrict__ W_ih, const float* __restrict__ W_hh,
    const float* __restrict__ b_ih, const float* __restrict__ b_hh,
    const float* __restrict__ h_cur, float* __restrict__ h_next)
{
    __shared__ float red[4][64];
    __shared__ float hrow[64];
    __shared__ float aggS[64];
    __shared__ float g1[192];
    __shared__ float h1S[64];
    __shared__ float g2i[192];
    __shared__ float g2h[192];

    int t = threadIdx.x;
    int row = blockIdx.x;               // b*64 + i
    int d = t & 63, jq = t >> 6;

    if (t < 64) hrow[t] = h_cur[row * 64 + t];

    float acc = 0.f;
    size_t ebase = (size_t)row * 64;
    for (int j = jq * 16; j < jq * 16 + 16; ++j) {
        float mk = edges[(ebase + j) * 16];     // wave-uniform broadcast
        if (mk != 0.f)
            acc += msgs[(ebase + j) * 64 + d];  // lane-d coalesced
    }
    red[jq][d] = acc;
    __syncthreads();

    if (t < 64) aggS[t] = red[0][t] + red[1][t] + red[2][t] + red[3][t];
    if (t < 192) {
        float g = b_ih[t];
        const float* wr = W_ih + t * 64;
#pragma unroll
        for (int k = 0; k < 64; ++k) g = fmaf(hrow[k], wr[k], g);
        g1[t] = g;
    }
    __syncthreads();
    // GRU cell 1, h_prev = 0 (gh = b_hh)
    if (t < 64) {
        float r1 = sigm(g1[t] + b_hh[t]);
        float z1 = sigm(g1[64 + t] + b_hh[64 + t]);
        float n1 = tanhf(g1[128 + t] + r1 * b_hh[128 + t]);
        h1S[t] = (1.f - z1) * n1;
    }
    __syncthreads();
    // GRU cell 2: x = agg, h = h1
    if (t < 192) {
        float gi = b_ih[t];
        float gh = b_hh[t];
        const float* wri = W_ih + t * 64;
        const float* wrh = W_hh + t * 64;
#pragma unroll
        for (int k = 0; k < 64; ++k) {
            gi = fmaf(aggS[k], wri[k], gi);
            gh = fmaf(h1S[k], wrh[k], gh);
        }
        g2i[t] = gi; g2h[t] = gh;
    }
    __syncthreads();
    if (t < 64) {
        float r = sigm(g2i[t] + g2h[t]);
        float z = sigm(g2i[64 + t] + g2h[64 + t]);
        float n = tanhf(g2i[128 + t] + r * g2h[128 + t]);
        h_next[row * 64 + t] = (1.f - z) * n + z * h1S[t];
    }
}

// ---------------------------------------------------------------------------
// Readout: 8 pairs per 256-thread block (halves W_r1/W_r2 L2 re-reads).
__global__ __launch_bounds__(256) void k_readout(
    const float* __restrict__ edges, const float* __restrict__ h,
    const float* __restrict__ W_r1, const float* __restrict__ b_r1,
    const float* __restrict__ W_r2, const float* __restrict__ b_r2,
    const float* __restrict__ W_r3, const float* __restrict__ b_r3,
    float* __restrict__ out)
{
    __shared__ float cat[8][144];
    __shared__ float a1[8][128];
    __shared__ float rbuf[8][128];
    int t = threadIdx.x, tt = t & 127, g = t >> 7;
    int p0 = blockIdx.x * 8;

    for (int idx = t; idx < 8 * 144; idx += 256) {
        int u = idx / 144, c = idx - u * 144;
        int p = p0 + u, b = p >> 12, e = p & 4095, ii = e >> 6, jj = e & 63;
        float v;
        if (c < 64)      v = h[(b * 64 + ii) * 64 + c];
        else if (c < 80) v = edges[(size_t)p * 16 + (c - 64)];
        else             v = h[(b * 64 + jj) * 64 + (c - 80)];
        cat[u][c] = v;
    }
    __syncthreads();

    float s[4];
    float bb = b_r1[tt];
    s[0] = s[1] = s[2] = s[3] = bb;
    for (int k = 0; k < 144; ++k) {
        float w = W_r1[k * 128 + tt];
#pragma unroll
        for (int u = 0; u < 4; ++u) s[u] = fmaf(cat[g * 4 + u][k], w, s[u]);
    }
#pragma unroll
    for (int u = 0; u < 4; ++u) a1[g * 4 + u][tt] = fmaxf(s[u], 0.f);
    __syncthreads();

    float bb2 = b_r2[tt];
    float s2[4];
    s2[0] = s2[1] = s2[2] = s2[3] = bb2;
    for (int k = 0; k < 128; ++k) {
        float w = W_r2[k * 128 + tt];
#pragma unroll
        for (int u = 0; u < 4; ++u) s2[u] = fmaf(a1[g * 4 + u][k], w, s2[u]);
    }
    float w3 = W_r3[tt];
#pragma unroll
    for (int u = 0; u < 4; ++u) rbuf[g * 4 + u][tt] = fmaxf(s2[u], 0.f) * w3;
    __syncthreads();

    if (t < 8) {
        float accv = b_r3[0];
        for (int k = 0; k < 128; ++k) accv += rbuf[t][k];
        out[p0 + t] = accv;
    }
}

// ---------------------------------------------------------------------------
extern "C" void kernel_launch(void* const* d_in, const int* in_sizes, int n_in,
                              void* d_out, int out_size, void* d_ws, size_t ws_size,
                              hipStream_t stream)
{
    const float* edges = (const float*)d_in[0];
    const float* nodes = (const float*)d_in[1];
    // d_in[2] adjacency: unused
    const float* W_en  = (const float*)d_in[3];
    const float* b_en  = (const float*)d_in[4];
    const float* W_agg = (const float*)d_in[5];
    const float* b_agg = (const float*)d_in[6];
    const float* W_ih  = (const float*)d_in[7];
    const float* W_hh  = (const float*)d_in[8];
    const float* b_ih  = (const float*)d_in[9];
    const float* b_hh  = (const float*)d_in[10];
    const float* W_r1  = (const float*)d_in[11];
    const float* b_r1  = (const float*)d_in[12];
    const float* W_r2  = (const float*)d_in[13];
    const float* b_r2  = (const float*)d_in[14];
    const float* W_r3  = (const float*)d_in[15];
    const float* b_r3  = (const float*)d_in[16];

    // workspace layout (≈4.3 MB)
    int*   cnt  = (int*)d_ws;
    int*   list = (int*)((char*)d_ws + 256);
    float* msgs = (float*)((char*)d_ws + 256 + 16384 * sizeof(int));   // 16384*64 f32
    float* hA   = msgs + 16384 * 64;
    float* hB   = hA + 4 * 64 * 64;

    hipMemsetAsync(cnt, 0, sizeof(int), stream);
    k_encode<<<64, 256, 0, stream>>>(nodes, W_en, b_en, hA);
    k_prep<<<64, 256, 0, stream>>>(edges, cnt, list);

    k_amsg<<<512, 256, 0, stream>>>(edges, W_agg, b_agg, hA, cnt, list, msgs);
    k_agg_gru<<<256, 256, 0, stream>>>(edges, msgs, W_ih, W_hh, b_ih, b_hh, hA, hB);
    k_amsg<<<512, 256, 0, stream>>>(edges, W_agg, b_agg, hB, cnt, list, msgs);
    k_agg_gru<<<256, 256, 0, stream>>>(edges, msgs, W_ih, W_hh, b_ih, b_hh, hB, hA);
    k_amsg<<<512, 256, 0, stream>>>(edges, W_agg, b_agg, hA, cnt, list, msgs);
    k_agg_gru<<<256, 256, 0, stream>>>(edges, msgs, W_ih, W_hh, b_ih, b_hh, hA, hB);

    k_readout<<<2048, 256, 0, stream>>>(edges, hB, W_r1, b_r1, W_r2, b_r2, W_r3, b_r3,
                                        (float*)d_out);
}

// Round 4
// 148.907 us; speedup vs baseline: 5.4272x; 1.8292x over previous
//
#include <hip/hip_runtime.h>

typedef float float4v __attribute__((ext_vector_type(4)));

__device__ __forceinline__ float sigm(float x) { return 1.0f / (1.0f + __expf(-x)); }

// ---------------------------------------------------------------------------
// h0 = relu(nodes @ W_en + b_en)   [4,64,32]@[32,64] -> [4,64,64]
__global__ void k_encode(const float* __restrict__ nodes, const float* __restrict__ W_en,
                         const float* __restrict__ b_en, float* __restrict__ h)
{
    int idx = blockIdx.x * 256 + threadIdx.x;   // 16384 = B*N*D
    int d = idx & 63, bn = idx >> 6;
    const float* np_ = nodes + bn * 32;
    float acc = b_en[d];
#pragma unroll
    for (int k = 0; k < 32; ++k)
        acc = fmaf(np_[k], W_en[k * 64 + d], acc);
    h[idx] = fmaxf(acc, 0.f);
}

// ---------------------------------------------------------------------------
// Compact the active-edge list (mask is constant across iterations).
// list order is nondeterministic (atomic bases) but downstream output is
// invariant: msgs are indexed by global edge id, aggregation is in fixed order.
__global__ void k_prep(const float* __restrict__ edges, int* __restrict__ cnt,
                       int* __restrict__ list)
{
    int e = blockIdx.x * 256 + threadIdx.x;     // 64 blocks cover 16384 edges
    bool act = edges[(size_t)e * 16] != 0.f;
    unsigned long long m = __ballot(act);
    int lane = threadIdx.x & 63;
    int base = 0;
    if (lane == 0) base = atomicAdd(cnt, __popcll(m));
    base = __shfl(base, 0, 64);
    if (act) {
        int pos = __popcll(m & ((1ull << lane) - 1ull));
        list[base + pos] = e;
    }
}

// ---------------------------------------------------------------------------
// Per-iteration messages for ACTIVE edges only:
//   msg[e,:] = relu(edges[e] @ W_agg + b_agg).reshape(64,64) @ h[b_e, j_e]
// Grid = 512 edge-tiles x 8 column-chunks. Block handles 32 edges x 8 output
// dims: stages ONE 16x512 W_agg chunk (32 KB) with a single barrier, then
// thread (s = t&31 edge, q = t>>5 dim) accumulates its message element.
// All inner-loop LDS reads are 2-address broadcasts (conflict-free).
__global__ __launch_bounds__(256) void k_amsg(
    const float* __restrict__ edges, const float* __restrict__ W_agg,
    const float* __restrict__ b_agg, const float* __restrict__ h_cur,
    const int* __restrict__ cnt, const int* __restrict__ list,
    float* __restrict__ msgs)
{
    __shared__ float Ws[16 * 512];  // 32 KB chunk of W_agg
    __shared__ float bs[512];

    int nact = cnt[0];
    int tile0 = (blockIdx.x >> 3) * 32;
    int ic = blockIdx.x & 7;        // column chunk: cols [ic*512, ic*512+512)
    if (tile0 >= nact) return;      // block-uniform exit (before any barrier)
    int nE = min(32, nact - tile0);

    int t = threadIdx.x;

    // --- stage W_agg chunk: coalesced global float4, bank-cycling LDS writes
    {
        const float* gbase = W_agg + ic * 512;
#pragma unroll
        for (int i = 0; i < 8; ++i) {
            int idx = i * 1024 + t * 4;         // flat float index in [16][512]
            int row = idx >> 9, col = idx & 511;
            *(float4v*)(Ws + idx) = *(const float4v*)(gbase + row * 4096 + col);
        }
        if (t < 128)
            *(float4v*)(bs + t * 4) = *(const float4v*)(b_agg + ic * 512 + t * 4);
    }

    // --- per-thread operands (overlap with staging latency)
    int s = t & 31, q = t >> 5;
    int e = list[tile0 + (s < nE ? s : 0)];
    int b = e >> 12, j = e & 63;

    float Er[16];
    {
        const float* ep = edges + (size_t)e * 16;
#pragma unroll
        for (int u = 0; u < 16; u += 4) {
            float4v v = *(const float4v*)(ep + u);
            Er[u] = v[0]; Er[u + 1] = v[1]; Er[u + 2] = v[2]; Er[u + 3] = v[3];
        }
    }
    float hr[64];
    {
        const float* hp = h_cur + ((b << 6) + j) * 64;
#pragma unroll
        for (int u = 0; u < 64; u += 4) {
            float4v v = *(const float4v*)(hp + u);
            hr[u] = v[0]; hr[u + 1] = v[1]; hr[u + 2] = v[2]; hr[u + 3] = v[3];
        }
    }
    __syncthreads();

    // --- A-row recompute + relu + dot with h_j for this thread's output dim
    float msum = 0.f;
#pragma unroll
    for (int jj = 0; jj < 64; jj += 4) {
        float4v a = *(const float4v*)(bs + q * 64 + jj);
#pragma unroll
        for (int k = 0; k < 16; ++k) {
            float4v w = *(const float4v*)(Ws + k * 512 + q * 64 + jj);  // broadcast
            a[0] = fmaf(Er[k], w[0], a[0]);
            a[1] = fmaf(Er[k], w[1], a[1]);
            a[2] = fmaf(Er[k], w[2], a[2]);
            a[3] = fmaf(Er[k], w[3], a[3]);
        }
        msum = fmaf(fmaxf(a[0], 0.f), hr[jj],     msum);
        msum = fmaf(fmaxf(a[1], 0.f), hr[jj + 1], msum);
        msum = fmaf(fmaxf(a[2], 0.f), hr[jj + 2], msum);
        msum = fmaf(fmaxf(a[3], 0.f), hr[jj + 3], msum);
    }
    if (s < nE) msgs[(size_t)e * 64 + ic * 8 + q] = msum;
}

// ---------------------------------------------------------------------------
// Masked aggregation over senders + fused 2-cell GRU. 256 blocks = (b,i) rows.
__global__ __launch_bounds__(256) void k_agg_gru(
    const float* __restrict__ edges, const float* __restrict__ msgs,
    const float* __restrict__ W_ih, const float* __restrict__ W_hh,
    const float* __restrict__ b_ih, const float* __restrict__ b_hh,
    const float* __restrict__ h_cur, float* __restrict__ h_next)
{
    __shared__ float red[4][64];
    __shared__ float hrow[64];
    __shared__ float aggS[64];
    __shared__ float g1[192];
    __shared__ float h1S[64];
    __shared__ float g2i[192];
    __shared__ float g2h[192];

    int t = threadIdx.x;
    int row = blockIdx.x;               // b*64 + i
    int d = t & 63, jq = t >> 6;

    if (t < 64) hrow[t] = h_cur[row * 64 + t];

    float acc = 0.f;
    size_t ebase = (size_t)row * 64;
    for (int j = jq * 16; j < jq * 16 + 16; ++j) {
        float mk = edges[(ebase + j) * 16];     // wave-uniform broadcast
        if (mk != 0.f)
            acc += msgs[(ebase + j) * 64 + d];  // lane-d coalesced
    }
    red[jq][d] = acc;
    __syncthreads();

    if (t < 64) aggS[t] = red[0][t] + red[1][t] + red[2][t] + red[3][t];
    if (t < 192) {
        float g = b_ih[t];
        const float* wr = W_ih + t * 64;
#pragma unroll
        for (int k = 0; k < 64; ++k) g = fmaf(hrow[k], wr[k], g);
        g1[t] = g;
    }
    __syncthreads();
    // GRU cell 1, h_prev = 0 (gh = b_hh)
    if (t < 64) {
        float r1 = sigm(g1[t] + b_hh[t]);
        float z1 = sigm(g1[64 + t] + b_hh[64 + t]);
        float n1 = tanhf(g1[128 + t] + r1 * b_hh[128 + t]);
        h1S[t] = (1.f - z1) * n1;
    }
    __syncthreads();
    // GRU cell 2: x = agg, h = h1
    if (t < 192) {
        float gi = b_ih[t];
        float gh = b_hh[t];
        const float* wri = W_ih + t * 64;
        const float* wrh = W_hh + t * 64;
#pragma unroll
        for (int k = 0; k < 64; ++k) {
            gi = fmaf(aggS[k], wri[k], gi);
            gh = fmaf(h1S[k], wrh[k], gh);
        }
        g2i[t] = gi; g2h[t] = gh;
    }
    __syncthreads();
    if (t < 64) {
        float r = sigm(g2i[t] + g2h[t]);
        float z = sigm(g2i[64 + t] + g2h[64 + t]);
        float n = tanhf(g2i[128 + t] + r * g2h[128 + t]);
        h_next[row * 64 + t] = (1.f - z) * n + z * h1S[t];
    }
}

// ---------------------------------------------------------------------------
// Readout: 16 pairs per 256-thread block (tt = output dim, g*8+u = pair slot).
__global__ __launch_bounds__(256) void k_readout(
    const float* __restrict__ edges, const float* __restrict__ h,
    const float* __restrict__ W_r1, const float* __restrict__ b_r1,
    const float* __restrict__ W_r2, const float* __restrict__ b_r2,
    const float* __restrict__ W_r3, const float* __restrict__ b_r3,
    float* __restrict__ out)
{
    __shared__ float cat[16][144];
    __shared__ float a1[16][128];
    __shared__ float rbuf[16][128];
    int t = threadIdx.x, tt = t & 127, g = t >> 7;
    int p0 = blockIdx.x * 16;

    for (int idx = t; idx < 16 * 144; idx += 256) {
        int u = idx / 144, c = idx - u * 144;
        int p = p0 + u, b = p >> 12, e = p & 4095, ii = e >> 6, jj = e & 63;
        float v;
        if (c < 64)      v = h[(b * 64 + ii) * 64 + c];
        else if (c < 80) v = edges[(size_t)p * 16 + (c - 64)];
        else             v = h[(b * 64 + jj) * 64 + (c - 80)];
        cat[u][c] = v;
    }
    __syncthreads();

    float s[8];
    float bb = b_r1[tt];
#pragma unroll
    for (int u = 0; u < 8; ++u) s[u] = bb;
    for (int k = 0; k < 144; ++k) {
        float w = W_r1[k * 128 + tt];
#pragma unroll
        for (int u = 0; u < 8; ++u) s[u] = fmaf(cat[g * 8 + u][k], w, s[u]);
    }
#pragma unroll
    for (int u = 0; u < 8; ++u) a1[g * 8 + u][tt] = fmaxf(s[u], 0.f);
    __syncthreads();

    float bb2 = b_r2[tt];
    float s2[8];
#pragma unroll
    for (int u = 0; u < 8; ++u) s2[u] = bb2;
    for (int k = 0; k < 128; ++k) {
        float w = W_r2[k * 128 + tt];
#pragma unroll
        for (int u = 0; u < 8; ++u) s2[u] = fmaf(a1[g * 8 + u][k], w, s2[u]);
    }
    float w3 = W_r3[tt];
#pragma unroll
    for (int u = 0; u < 8; ++u) rbuf[g * 8 + u][tt] = fmaxf(s2[u], 0.f) * w3;
    __syncthreads();

    if (t < 16) {
        float accv = b_r3[0];
        for (int k = 0; k < 128; ++k) accv += rbuf[t][k];
        out[p0 + t] = accv;
    }
}

// ---------------------------------------------------------------------------
extern "C" void kernel_launch(void* const* d_in, const int* in_sizes, int n_in,
                              void* d_out, int out_size, void* d_ws, size_t ws_size,
                              hipStream_t stream)
{
    const float* edges = (const float*)d_in[0];
    const float* nodes = (const float*)d_in[1];
    // d_in[2] adjacency: unused
    const float* W_en  = (const float*)d_in[3];
    const float* b_en  = (const float*)d_in[4];
    const float* W_agg = (const float*)d_in[5];
    const float* b_agg = (const float*)d_in[6];
    const float* W_ih  = (const float*)d_in[7];
    const float* W_hh  = (const float*)d_in[8];
    const float* b_ih  = (const float*)d_in[9];
    const float* b_hh  = (const float*)d_in[10];
    const float* W_r1  = (const float*)d_in[11];
    const float* b_r1  = (const float*)d_in[12];
    const float* W_r2  = (const float*)d_in[13];
    const float* b_r2  = (const float*)d_in[14];
    const float* W_r3  = (const float*)d_in[15];
    const float* b_r3  = (const float*)d_in[16];

    // workspace layout (~4.3 MB)
    int*   cnt  = (int*)d_ws;
    int*   list = (int*)((char*)d_ws + 256);
    float* msgs = (float*)((char*)d_ws + 256 + 16384 * sizeof(int));   // 16384*64 f32
    float* hA   = msgs + 16384 * 64;
    float* hB   = hA + 4 * 64 * 64;

    hipMemsetAsync(cnt, 0, sizeof(int), stream);
    k_encode<<<64, 256, 0, stream>>>(nodes, W_en, b_en, hA);
    k_prep<<<64, 256, 0, stream>>>(edges, cnt, list);

    k_amsg<<<4096, 256, 0, stream>>>(edges, W_agg, b_agg, hA, cnt, list, msgs);
    k_agg_gru<<<256, 256, 0, stream>>>(edges, msgs, W_ih, W_hh, b_ih, b_hh, hA, hB);
    k_amsg<<<4096, 256, 0, stream>>>(edges, W_agg, b_agg, hB, cnt, list, msgs);
    k_agg_gru<<<256, 256, 0, stream>>>(edges, msgs, W_ih, W_hh, b_ih, b_hh, hB, hA);
    k_amsg<<<4096, 256, 0, stream>>>(edges, W_agg, b_agg, hA, cnt, list, msgs);
    k_agg_gru<<<256, 256, 0, stream>>>(edges, msgs, W_ih, W_hh, b_ih, b_hh, hA, hB);

    k_readout<<<1024, 256, 0, stream>>>(edges, hB, W_r1, b_r1, W_r2, b_r2, W_r3, b_r3,
                                        (float*)d_out);
}

// Round 5
// 120.633 us; speedup vs baseline: 6.6992x; 1.2344x over previous
//
#include <hip/hip_runtime.h>

typedef float float4v __attribute__((ext_vector_type(4)));
typedef float float2v __attribute__((ext_vector_type(2)));

__device__ __forceinline__ float sigm(float x) { return 1.0f / (1.0f + __expf(-x)); }

#define HS_LD 68   // padded leading dim (floats) for staged h in LDS

// ---------------------------------------------------------------------------
// k_pre: blocks 0..63 -> h0 = relu(nodes @ W_en + b_en)
//        blocks 64..127 -> per-row active-edge compaction (ballot, no atomics)
__global__ __launch_bounds__(256) void k_pre(
    const float* __restrict__ nodes, const float* __restrict__ W_en,
    const float* __restrict__ b_en, const float* __restrict__ edges,
    float* __restrict__ h0, int* __restrict__ rowcnt, int* __restrict__ rowlist)
{
    int t = threadIdx.x;
    if (blockIdx.x < 64) {
        int idx = blockIdx.x * 256 + t;          // 16384 = B*N*D
        int d = idx & 63, bn = idx >> 6;
        const float* np_ = nodes + bn * 32;
        float acc = b_en[d];
#pragma unroll
        for (int k = 0; k < 32; ++k)
            acc = fmaf(np_[k], W_en[k * 64 + d], acc);
        h0[idx] = fmaxf(acc, 0.f);
    } else {
        int blk = blockIdx.x - 64;               // 0..63
        int w = t >> 6, lane = t & 63;
        int row = blk * 4 + w;                   // 0..255 (= b*64 + i)
        bool act = edges[((size_t)row * 64 + lane) * 16] != 0.f;
        unsigned long long m = __ballot(act);
        if (lane == 0) rowcnt[row] = __popcll(m);
        if (act) {
            int pos = __popcll(m & ((1ull << lane) - 1ull));
            rowlist[row * 64 + pos] = lane;      // ascending j: deterministic
        }
    }
}

// ---------------------------------------------------------------------------
// One message-passing iteration, W-in-registers / scalar-streamed edges:
//   agg[row, dim] = sum_{j active} relu(edges[row,j] @ W_agg + b_agg)[dim,:] . h[b,j]
// Grid = 1024 blocks: rg = blockIdx>>3 (row-pair), ic = blockIdx&7 (8-dim chunk).
// Lane (wv = t>>6, l) owns dim = ic*8 + wv*2 + (l>>5), A-row cols {2*c2, 2*c2+1}.
// Per edge: 4 wave-uniform float4 loads (scalar path) + 32 reg-FMA + 1 ds_read_b64.
__global__ __launch_bounds__(256, 4) void k_iter(
    const float* __restrict__ edges, const float* __restrict__ W_agg,
    const float* __restrict__ b_agg, const float* __restrict__ h_cur,
    const int* __restrict__ rowcnt, const int* __restrict__ rowlist,
    float* __restrict__ agg)
{
    __shared__ float hs[64 * HS_LD];   // h of this batch, padded rows (17.4 KB)

    int t = threadIdx.x;
    int rg = blockIdx.x >> 3, ic = blockIdx.x & 7;
    int r0 = rg * 2;                   // two consecutive rows, same batch
    int b = r0 >> 6;
    int wv = t >> 6, lane = t & 63;
    int dim = ic * 8 + wv * 2 + (lane >> 5);
    int c2 = lane & 31;

    // stage h[b] (64x64) into LDS, padded (write conflicts 2-way = free)
    {
        int n = t >> 2, seg = t & 3;
        const float* gp = h_cur + ((b << 6) + n) * 64 + seg * 16;
        float* lp = hs + n * HS_LD + seg * 16;
#pragma unroll
        for (int u = 0; u < 16; u += 4)
            *(float4v*)(lp + u) = *(const float4v*)(gp + u);
    }

    // resident W fragment: w[k] = W_agg[k][dim*64 + 2*c2 + {0,1}]
    float2v w[16];
    {
        const float* wp = W_agg + dim * 64 + c2 * 2;
#pragma unroll
        for (int k = 0; k < 16; ++k)
            w[k] = *(const float2v*)(wp + k * 4096);
    }
    float2v bias = *(const float2v*)(b_agg + dim * 64 + c2 * 2);

    __syncthreads();

    size_t ebase = ((size_t)b) << 12;
#pragma unroll
    for (int rr = 0; rr < 2; ++rr) {
        int row = r0 + rr;
        int ri = row & 63;
        int nE = rowcnt[row];          // wave-uniform
        float rsum = 0.f;

        // 1-deep software pipeline over active edges
        int ejn = 0;
        float4v n0 = {0,0,0,0}, n1 = n0, n2 = n0, n3 = n0;
        if (nE > 0) {
            ejn = __builtin_amdgcn_readfirstlane(rowlist[row * 64]);
            const float* ep = edges + (ebase + (size_t)(ri * 64 + ejn)) * 16;
            n0 = *(const float4v*)ep;      n1 = *(const float4v*)(ep + 4);
            n2 = *(const float4v*)(ep + 8); n3 = *(const float4v*)(ep + 12);
        }
        for (int idx = 0; idx < nE; ++idx) {
            int ejc = ejn;
            float4v e0 = n0, e1 = n1, e2 = n2, e3 = n3;
            if (idx + 1 < nE) {
                ejn = __builtin_amdgcn_readfirstlane(rowlist[row * 64 + idx + 1]);
                const float* ep = edges + (ebase + (size_t)(ri * 64 + ejn)) * 16;
                n0 = *(const float4v*)ep;      n1 = *(const float4v*)(ep + 4);
                n2 = *(const float4v*)(ep + 8); n3 = *(const float4v*)(ep + 12);
            }
            float a0 = bias[0], a1 = bias[1];
#pragma unroll
            for (int k = 0; k < 4; ++k) { a0 = fmaf(e0[k], w[k][0], a0);      a1 = fmaf(e0[k], w[k][1], a1); }
#pragma unroll
            for (int k = 0; k < 4; ++k) { a0 = fmaf(e1[k], w[4 + k][0], a0);  a1 = fmaf(e1[k], w[4 + k][1], a1); }
#pragma unroll
            for (int k = 0; k < 4; ++k) { a0 = fmaf(e2[k], w[8 + k][0], a0);  a1 = fmaf(e2[k], w[8 + k][1], a1); }
#pragma unroll
            for (int k = 0; k < 4; ++k) { a0 = fmaf(e3[k], w[12 + k][0], a0); a1 = fmaf(e3[k], w[12 + k][1], a1); }
            float2v hv = *(const float2v*)(hs + ejc * HS_LD + c2 * 2);
            rsum = fmaf(fmaxf(a0, 0.f), hv[0], rsum);
            rsum = fmaf(fmaxf(a1, 0.f), hv[1], rsum);
        }
        // reduce over the 32 c2-lanes of each half-wave
#pragma unroll
        for (int m = 1; m < 32; m <<= 1) rsum += __shfl_xor(rsum, m, 64);
        if (c2 == 0) agg[row * 64 + dim] = rsum;
    }
}

// ---------------------------------------------------------------------------
// Fused 2-cell GRU per row (aggregation already done). 256 blocks.
__global__ __launch_bounds__(256) void k_gru(
    const float* __restrict__ agg, const float* __restrict__ W_ih,
    const float* __restrict__ W_hh, const float* __restrict__ b_ih,
    const float* __restrict__ b_hh, const float* __restrict__ h_cur,
    float* __restrict__ h_next)
{
    __shared__ float hrow[64];
    __shared__ float aggS[64];
    __shared__ float g1[192];
    __shared__ float h1S[64];
    __shared__ float g2i[192];
    __shared__ float g2h[192];

    int t = threadIdx.x;
    int row = blockIdx.x;

    if (t < 64) hrow[t] = h_cur[row * 64 + t];
    if (t >= 64 && t < 128) aggS[t - 64] = agg[row * 64 + (t - 64)];
    __syncthreads();

    if (t < 192) {
        float g = b_ih[t];
        const float* wr = W_ih + t * 64;
#pragma unroll
        for (int k = 0; k < 64; ++k) g = fmaf(hrow[k], wr[k], g);
        g1[t] = g;
    }
    __syncthreads();
    // GRU cell 1, h_prev = 0 (gh = b_hh)
    if (t < 64) {
        float r1 = sigm(g1[t] + b_hh[t]);
        float z1 = sigm(g1[64 + t] + b_hh[64 + t]);
        float n1 = tanhf(g1[128 + t] + r1 * b_hh[128 + t]);
        h1S[t] = (1.f - z1) * n1;
    }
    __syncthreads();
    // GRU cell 2: x = agg, h = h1
    if (t < 192) {
        float gi = b_ih[t];
        float gh = b_hh[t];
        const float* wri = W_ih + t * 64;
        const float* wrh = W_hh + t * 64;
#pragma unroll
        for (int k = 0; k < 64; ++k) {
            gi = fmaf(aggS[k], wri[k], gi);
            gh = fmaf(h1S[k], wrh[k], gh);
        }
        g2i[t] = gi; g2h[t] = gh;
    }
    __syncthreads();
    if (t < 64) {
        float r = sigm(g2i[t] + g2h[t]);
        float z = sigm(g2i[64 + t] + g2h[64 + t]);
        float n = tanhf(g2i[128 + t] + r * g2h[128 + t]);
        h_next[row * 64 + t] = (1.f - z) * n + z * h1S[t];
    }
}

// ---------------------------------------------------------------------------
// Readout: 16 pairs per 256-thread block; cat reads batched as float4 (b128).
__global__ __launch_bounds__(256) void k_readout(
    const float* __restrict__ edges, const float* __restrict__ h,
    const float* __restrict__ W_r1, const float* __restrict__ b_r1,
    const float* __restrict__ W_r2, const float* __restrict__ b_r2,
    const float* __restrict__ W_r3, const float* __restrict__ b_r3,
    float* __restrict__ out)
{
    __shared__ float cat[16][144];
    __shared__ float a1[16][128];
    __shared__ float rbuf[16][128];
    int t = threadIdx.x, tt = t & 127, g = t >> 7;
    int p0 = blockIdx.x * 16;

    for (int idx = t; idx < 16 * 144; idx += 256) {
        int u = idx / 144, c = idx - u * 144;
        int p = p0 + u, b = p >> 12, e = p & 4095, ii = e >> 6, jj = e & 63;
        float v;
        if (c < 64)      v = h[(b * 64 + ii) * 64 + c];
        else if (c < 80) v = edges[(size_t)p * 16 + (c - 64)];
        else             v = h[(b * 64 + jj) * 64 + (c - 80)];
        cat[u][c] = v;
    }
    __syncthreads();

    float s[8];
    float bb = b_r1[tt];
#pragma unroll
    for (int u = 0; u < 8; ++u) s[u] = bb;
    for (int k4 = 0; k4 < 36; ++k4) {
        float4v cv[8];
#pragma unroll
        for (int u = 0; u < 8; ++u)
            cv[u] = *(const float4v*)&cat[g * 8 + u][k4 * 4];
#pragma unroll
        for (int kk = 0; kk < 4; ++kk) {
            float wv_ = W_r1[(k4 * 4 + kk) * 128 + tt];
#pragma unroll
            for (int u = 0; u < 8; ++u) s[u] = fmaf(cv[u][kk], wv_, s[u]);
        }
    }
#pragma unroll
    for (int u = 0; u < 8; ++u) a1[g * 8 + u][tt] = fmaxf(s[u], 0.f);
    __syncthreads();

    float bb2 = b_r2[tt];
    float s2[8];
#pragma unroll
    for (int u = 0; u < 8; ++u) s2[u] = bb2;
    for (int k4 = 0; k4 < 32; ++k4) {
        float4v cv[8];
#pragma unroll
        for (int u = 0; u < 8; ++u)
            cv[u] = *(const float4v*)&a1[g * 8 + u][k4 * 4];
#pragma unroll
        for (int kk = 0; kk < 4; ++kk) {
            float wv_ = W_r2[(k4 * 4 + kk) * 128 + tt];
#pragma unroll
            for (int u = 0; u < 8; ++u) s2[u] = fmaf(cv[u][kk], wv_, s2[u]);
        }
    }
    float w3 = W_r3[tt];
#pragma unroll
    for (int u = 0; u < 8; ++u) rbuf[g * 8 + u][tt] = fmaxf(s2[u], 0.f) * w3;
    __syncthreads();

    if (t < 16) {
        float accv = b_r3[0];
        for (int k = 0; k < 128; ++k) accv += rbuf[t][k];
        out[p0 + t] = accv;
    }
}

// ---------------------------------------------------------------------------
extern "C" void kernel_launch(void* const* d_in, const int* in_sizes, int n_in,
                              void* d_out, int out_size, void* d_ws, size_t ws_size,
                              hipStream_t stream)
{
    const float* edges = (const float*)d_in[0];
    const float* nodes = (const float*)d_in[1];
    // d_in[2] adjacency: unused
    const float* W_en  = (const float*)d_in[3];
    const float* b_en  = (const float*)d_in[4];
    const float* W_agg = (const float*)d_in[5];
    const float* b_agg = (const float*)d_in[6];
    const float* W_ih  = (const float*)d_in[7];
    const float* W_hh  = (const float*)d_in[8];
    const float* b_ih  = (const float*)d_in[9];
    const float* b_hh  = (const float*)d_in[10];
    const float* W_r1  = (const float*)d_in[11];
    const float* b_r1  = (const float*)d_in[12];
    const float* W_r2  = (const float*)d_in[13];
    const float* b_r2  = (const float*)d_in[14];
    const float* W_r3  = (const float*)d_in[15];
    const float* b_r3  = (const float*)d_in[16];

    // workspace layout (~320 KB, all rewritten deterministically every call)
    int*   rowcnt  = (int*)d_ws;                         // 256 ints
    int*   rowlist = rowcnt + 256;                       // 256*64 ints
    float* agg     = (float*)(rowlist + 256 * 64);       // 256*64 f32
    float* hA      = agg + 256 * 64;                     // [4,64,64]
    float* hB      = hA + 4 * 64 * 64;                   // [4,64,64]

    k_pre<<<128, 256, 0, stream>>>(nodes, W_en, b_en, edges, hA, rowcnt, rowlist);

    k_iter<<<1024, 256, 0, stream>>>(edges, W_agg, b_agg, hA, rowcnt, rowlist, agg);
    k_gru<<<256, 256, 0, stream>>>(agg, W_ih, W_hh, b_ih, b_hh, hA, hB);
    k_iter<<<1024, 256, 0, stream>>>(edges, W_agg, b_agg, hB, rowcnt, rowlist, agg);
    k_gru<<<256, 256, 0, stream>>>(agg, W_ih, W_hh, b_ih, b_hh, hB, hA);
    k_iter<<<1024, 256, 0, stream>>>(edges, W_agg, b_agg, hA, rowcnt, rowlist, agg);
    k_gru<<<256, 256, 0, stream>>>(agg, W_ih, W_hh, b_ih, b_hh, hA, hB);

    k_readout<<<1024, 256, 0, stream>>>(edges, hB, W_r1, b_r1, W_r2, b_r2, W_r3, b_r3,
                                        (float*)d_out);
}

// Round 6
// 106.481 us; speedup vs baseline: 7.5895x; 1.1329x over previous
//
#include <hip/hip_runtime.h>

typedef float float4v __attribute__((ext_vector_type(4)));
typedef float float2v __attribute__((ext_vector_type(2)));

__device__ __forceinline__ float sigm(float x) { return 1.0f / (1.0f + __expf(-x)); }

#define HS_LD 68   // padded leading dim (floats) for staged h in LDS

// ---------------------------------------------------------------------------
// k_pre: blocks 0..63    -> h0 = relu(nodes @ W_en + b_en)
//        blocks 64..127  -> per-row active-edge compaction (ballot, no atomics)
//        blocks 128..1151-> EW[p][d] = edges[p] @ W1b  (iteration-independent
//                           readout layer-1 edge term; W1b = W_r1 rows 64..79)
__global__ __launch_bounds__(256) void k_pre(
    const float* __restrict__ nodes, const float* __restrict__ W_en,
    const float* __restrict__ b_en, const float* __restrict__ edges,
    const float* __restrict__ W_r1,
    float* __restrict__ h0, int* __restrict__ rowcnt, int* __restrict__ rowlist,
    float* __restrict__ EW)
{
    __shared__ float eS[16][16];
    int t = threadIdx.x;
    if (blockIdx.x < 64) {
        int idx = blockIdx.x * 256 + t;          // 16384 = B*N*D
        int d = idx & 63, bn = idx >> 6;
        const float* np_ = nodes + bn * 32;
        float acc = b_en[d];
#pragma unroll
        for (int k = 0; k < 32; ++k)
            acc = fmaf(np_[k], W_en[k * 64 + d], acc);
        h0[idx] = fmaxf(acc, 0.f);
    } else if (blockIdx.x < 128) {
        int blk = blockIdx.x - 64;               // 0..63
        int w = t >> 6, lane = t & 63;
        int row = blk * 4 + w;                   // 0..255 (= b*64 + i)
        bool act = edges[((size_t)row * 64 + lane) * 16] != 0.f;
        unsigned long long m = __ballot(act);
        if (lane == 0) rowcnt[row] = __popcll(m);
        if (act) {
            int pos = __popcll(m & ((1ull << lane) - 1ull));
            rowlist[row * 64 + pos] = lane;      // ascending j: deterministic
        }
    } else {
        int eb = blockIdx.x - 128;               // 0..1023, 16 pairs each
        int base = eb * 16;
        eS[t >> 4][t & 15] = edges[(size_t)base * 16 + t];   // 256 floats
        __syncthreads();
        int pp = t >> 7, d = t & 127;
#pragma unroll
        for (int pi = 0; pi < 8; ++pi) {
            int pl = pp * 8 + pi;
            float acc = 0.f;
#pragma unroll
            for (int k = 0; k < 16; ++k)
                acc = fmaf(eS[pl][k], W_r1[(64 + k) * 128 + d], acc);
            EW[(size_t)(base + pl) * 128 + d] = acc;
        }
    }
}

// ---------------------------------------------------------------------------
// One message-passing iteration, W-in-registers / scalar-streamed edges:
//   agg[row, dim] = sum_{j active} relu(edges[row,j] @ W_agg + b_agg)[dim,:] . h[b,j]
__global__ __launch_bounds__(256, 4) void k_iter(
    const float* __restrict__ edges, const float* __restrict__ W_agg,
    const float* __restrict__ b_agg, const float* __restrict__ h_cur,
    const int* __restrict__ rowcnt, const int* __restrict__ rowlist,
    float* __restrict__ agg)
{
    __shared__ float hs[64 * HS_LD];   // h of this batch, padded rows (17.4 KB)

    int t = threadIdx.x;
    int rg = blockIdx.x >> 3, ic = blockIdx.x & 7;
    int r0 = rg * 2;                   // two consecutive rows, same batch
    int b = r0 >> 6;
    int wv = t >> 6, lane = t & 63;
    int dim = ic * 8 + wv * 2 + (lane >> 5);
    int c2 = lane & 31;

    // stage h[b] (64x64) into LDS, padded
    {
        int n = t >> 2, seg = t & 3;
        const float* gp = h_cur + ((b << 6) + n) * 64 + seg * 16;
        float* lp = hs + n * HS_LD + seg * 16;
#pragma unroll
        for (int u = 0; u < 16; u += 4)
            *(float4v*)(lp + u) = *(const float4v*)(gp + u);
    }

    // resident W fragment: w[k] = W_agg[k][dim*64 + 2*c2 + {0,1}]
    float2v w[16];
    {
        const float* wp = W_agg + dim * 64 + c2 * 2;
#pragma unroll
        for (int k = 0; k < 16; ++k)
            w[k] = *(const float2v*)(wp + k * 4096);
    }
    float2v bias = *(const float2v*)(b_agg + dim * 64 + c2 * 2);

    __syncthreads();

    size_t ebase = ((size_t)b) << 12;
#pragma unroll
    for (int rr = 0; rr < 2; ++rr) {
        int row = r0 + rr;
        int ri = row & 63;
        int nE = rowcnt[row];          // wave-uniform
        float rsum = 0.f;

        int ejn = 0;
        float4v n0 = {0,0,0,0}, n1 = n0, n2 = n0, n3 = n0;
        if (nE > 0) {
            ejn = __builtin_amdgcn_readfirstlane(rowlist[row * 64]);
            const float* ep = edges + (ebase + (size_t)(ri * 64 + ejn)) * 16;
            n0 = *(const float4v*)ep;      n1 = *(const float4v*)(ep + 4);
            n2 = *(const float4v*)(ep + 8); n3 = *(const float4v*)(ep + 12);
        }
        for (int idx = 0; idx < nE; ++idx) {
            int ejc = ejn;
            float4v e0 = n0, e1 = n1, e2 = n2, e3 = n3;
            if (idx + 1 < nE) {
                ejn = __builtin_amdgcn_readfirstlane(rowlist[row * 64 + idx + 1]);
                const float* ep = edges + (ebase + (size_t)(ri * 64 + ejn)) * 16;
                n0 = *(const float4v*)ep;      n1 = *(const float4v*)(ep + 4);
                n2 = *(const float4v*)(ep + 8); n3 = *(const float4v*)(ep + 12);
            }
            float a0 = bias[0], a1 = bias[1];
#pragma unroll
            for (int k = 0; k < 4; ++k) { a0 = fmaf(e0[k], w[k][0], a0);      a1 = fmaf(e0[k], w[k][1], a1); }
#pragma unroll
            for (int k = 0; k < 4; ++k) { a0 = fmaf(e1[k], w[4 + k][0], a0);  a1 = fmaf(e1[k], w[4 + k][1], a1); }
#pragma unroll
            for (int k = 0; k < 4; ++k) { a0 = fmaf(e2[k], w[8 + k][0], a0);  a1 = fmaf(e2[k], w[8 + k][1], a1); }
#pragma unroll
            for (int k = 0; k < 4; ++k) { a0 = fmaf(e3[k], w[12 + k][0], a0); a1 = fmaf(e3[k], w[12 + k][1], a1); }
            float2v hv = *(const float2v*)(hs + ejc * HS_LD + c2 * 2);
            rsum = fmaf(fmaxf(a0, 0.f), hv[0], rsum);
            rsum = fmaf(fmaxf(a1, 0.f), hv[1], rsum);
        }
#pragma unroll
        for (int m = 1; m < 32; m <<= 1) rsum += __shfl_xor(rsum, m, 64);
        if (c2 == 0) agg[row * 64 + dim] = rsum;
    }
}

// ---------------------------------------------------------------------------
// Fused 2-cell GRU per row. On the last iteration (emit=1) also emits the
// per-node readout terms: Ha[row] = h_new @ W1a + b_r1, Hc[row] = h_new @ W1c.
__global__ __launch_bounds__(256) void k_gru(
    const float* __restrict__ agg, const float* __restrict__ W_ih,
    const float* __restrict__ W_hh, const float* __restrict__ b_ih,
    const float* __restrict__ b_hh, const float* __restrict__ h_cur,
    float* __restrict__ h_next,
    const float* __restrict__ W_r1, const float* __restrict__ b_r1,
    float* __restrict__ Ha, float* __restrict__ Hc, int emit)
{
    __shared__ float hrow[64];
    __shared__ float aggS[64];
    __shared__ float g1[192];
    __shared__ float h1S[64];
    __shared__ float g2i[192];
    __shared__ float g2h[192];
    __shared__ float hnS[64];

    int t = threadIdx.x;
    int row = blockIdx.x;

    if (t < 64) hrow[t] = h_cur[row * 64 + t];
    if (t >= 64 && t < 128) aggS[t - 64] = agg[row * 64 + (t - 64)];
    __syncthreads();

    if (t < 192) {
        float g = b_ih[t];
        const float* wr = W_ih + t * 64;
#pragma unroll
        for (int k = 0; k < 64; ++k) g = fmaf(hrow[k], wr[k], g);
        g1[t] = g;
    }
    __syncthreads();
    if (t < 64) {
        float r1 = sigm(g1[t] + b_hh[t]);
        float z1 = sigm(g1[64 + t] + b_hh[64 + t]);
        float n1 = tanhf(g1[128 + t] + r1 * b_hh[128 + t]);
        h1S[t] = (1.f - z1) * n1;
    }
    __syncthreads();
    if (t < 192) {
        float gi = b_ih[t];
        float gh = b_hh[t];
        const float* wri = W_ih + t * 64;
        const float* wrh = W_hh + t * 64;
#pragma unroll
        for (int k = 0; k < 64; ++k) {
            gi = fmaf(aggS[k], wri[k], gi);
            gh = fmaf(h1S[k], wrh[k], gh);
        }
        g2i[t] = gi; g2h[t] = gh;
    }
    __syncthreads();
    if (t < 64) {
        float r = sigm(g2i[t] + g2h[t]);
        float z = sigm(g2i[64 + t] + g2h[64 + t]);
        float n = tanhf(g2i[128 + t] + r * g2h[128 + t]);
        float hn = (1.f - z) * n + z * h1S[t];
        h_next[row * 64 + t] = hn;
        hnS[t] = hn;
    }
    __syncthreads();
    if (emit) {
        int m = t >> 7, d = t & 127;     // m=0 -> Ha, m=1 -> Hc
        const float* wbase = W_r1 + (m ? 80 * 128 : 0) + d;
        float acc = m ? 0.f : b_r1[d];
#pragma unroll
        for (int k = 0; k < 64; ++k)
            acc = fmaf(hnS[k], wbase[k * 128], acc);
        if (m == 0) Ha[row * 128 + d] = acc;
        else        Hc[row * 128 + d] = acc;
    }
}

// ---------------------------------------------------------------------------
// Readout, factored: a1 = relu(Ha[i] + Hc[j] + EW[p]); out = relu(a1@W_r2+b2)@W_r3+b3
// One block per receiver row i: 512 threads = 32 dim-threads (4 dims) x 16
// pair-groups (4 pairs). Hc[b] staged in LDS (reused for a1 after barrier);
// all layer-2 LDS reads are half-wave broadcasts.
__global__ __launch_bounds__(512) void k_readout(
    const float* __restrict__ EW, const float* __restrict__ Ha,
    const float* __restrict__ Hc,
    const float* __restrict__ W_r2, const float* __restrict__ b_r2,
    const float* __restrict__ W_r3, const float* __restrict__ b_r3,
    float* __restrict__ out)
{
    __shared__ float HcS[64][128];   // 32.8 KB; becomes a1 after layer 1
    __shared__ float HaS[128];

    int t = threadIdx.x;
    int row = blockIdx.x;            // b*64 + i
    int b = row >> 6;
    int td = t & 31, pg = t >> 5;    // dims td*4..+3 ; pairs pg*4..+3

    // stage Hc of this batch (64 nodes x 128) + Ha[row]
    {
        const float* src = Hc + (size_t)(b << 6) * 128;
        float* dst = &HcS[0][0];
#pragma unroll
        for (int r = 0; r < 4; ++r) {
            int off = (r * 512 + t) * 4;
            *(float4v*)(dst + off) = *(const float4v*)(src + off);
        }
        if (t < 32)
            *(float4v*)(HaS + t * 4) = *(const float4v*)(Ha + row * 128 + t * 4);
    }
    __syncthreads();

    // layer 1: a1 = relu(Ha + Hc[j] + EW[p])
    float4v a1r[4];
#pragma unroll
    for (int pi = 0; pi < 4; ++pi) {
        int p = pg * 4 + pi;
        float4v acc = *(const float4v*)(HaS + td * 4);
        float4v hc  = *(const float4v*)(&HcS[p][td * 4]);
        float4v ew  = *(const float4v*)(EW + ((size_t)row * 64 + p) * 128 + td * 4);
#pragma unroll
        for (int u = 0; u < 4; ++u)
            a1r[pi][u] = fmaxf(acc[u] + hc[u] + ew[u], 0.f);
    }
    __syncthreads();
#pragma unroll
    for (int pi = 0; pi < 4; ++pi)
        *(float4v*)(&HcS[pg * 4 + pi][td * 4]) = a1r[pi];
    __syncthreads();

    // layer 2: acc2[pi] = b_r2 + a1[p] @ W_r2 (4 dims per thread)
    float4v bb2 = *(const float4v*)(b_r2 + td * 4);
    float4v acc2_0 = bb2, acc2_1 = bb2, acc2_2 = bb2, acc2_3 = bb2;
    for (int k4 = 0; k4 < 32; ++k4) {
        float4v w0 = *(const float4v*)(W_r2 + (k4 * 4 + 0) * 128 + td * 4);
        float4v w1 = *(const float4v*)(W_r2 + (k4 * 4 + 1) * 128 + td * 4);
        float4v w2 = *(const float4v*)(W_r2 + (k4 * 4 + 2) * 128 + td * 4);
        float4v w3 = *(const float4v*)(W_r2 + (k4 * 4 + 3) * 128 + td * 4);
#pragma unroll
        for (int pi = 0; pi < 4; ++pi) {
            float4v a1v = *(const float4v*)(&HcS[pg * 4 + pi][k4 * 4]);  // broadcast
            float4v* acc = (pi == 0) ? &acc2_0 : (pi == 1) ? &acc2_1
                         : (pi == 2) ? &acc2_2 : &acc2_3;
#pragma unroll
            for (int u = 0; u < 4; ++u) {
                (*acc)[u] = fmaf(a1v[0], w0[u], (*acc)[u]);
                (*acc)[u] = fmaf(a1v[1], w1[u], (*acc)[u]);
                (*acc)[u] = fmaf(a1v[2], w2[u], (*acc)[u]);
                (*acc)[u] = fmaf(a1v[3], w3[u], (*acc)[u]);
            }
        }
    }

    // layer 3: dot(relu(a2), w3) reduced over the 32 dim-threads
    float4v w3v = *(const float4v*)(W_r3 + td * 4);
    float b3 = b_r3[0];
#pragma unroll
    for (int pi = 0; pi < 4; ++pi) {
        float4v a = (pi == 0) ? acc2_0 : (pi == 1) ? acc2_1
                  : (pi == 2) ? acc2_2 : acc2_3;
        float part = fmaxf(a[0], 0.f) * w3v[0] + fmaxf(a[1], 0.f) * w3v[1]
                   + fmaxf(a[2], 0.f) * w3v[2] + fmaxf(a[3], 0.f) * w3v[3];
#pragma unroll
        for (int m = 1; m < 32; m <<= 1) part += __shfl_xor(part, m, 64);
        if (td == 0) out[row * 64 + pg * 4 + pi] = part + b3;
    }
}

// ---------------------------------------------------------------------------
extern "C" void kernel_launch(void* const* d_in, const int* in_sizes, int n_in,
                              void* d_out, int out_size, void* d_ws, size_t ws_size,
                              hipStream_t stream)
{
    const float* edges = (const float*)d_in[0];
    const float* nodes = (const float*)d_in[1];
    // d_in[2] adjacency: unused
    const float* W_en  = (const float*)d_in[3];
    const float* b_en  = (const float*)d_in[4];
    const float* W_agg = (const float*)d_in[5];
    const float* b_agg = (const float*)d_in[6];
    const float* W_ih  = (const float*)d_in[7];
    const float* W_hh  = (const float*)d_in[8];
    const float* b_ih  = (const float*)d_in[9];
    const float* b_hh  = (const float*)d_in[10];
    const float* W_r1  = (const float*)d_in[11];
    const float* b_r1  = (const float*)d_in[12];
    const float* W_r2  = (const float*)d_in[13];
    const float* b_r2  = (const float*)d_in[14];
    const float* W_r3  = (const float*)d_in[15];
    const float* b_r3  = (const float*)d_in[16];

    // workspace layout (~8.7 MB, fully rewritten every call)
    int*   rowcnt  = (int*)d_ws;                         // 256
    int*   rowlist = rowcnt + 256;                       // 16384
    float* agg     = (float*)(rowlist + 16384);          // 16384
    float* hA      = agg + 16384;                        // 16384
    float* hB      = hA + 16384;                         // 16384
    float* Ha      = hB + 16384;                         // 256*128
    float* Hc      = Ha + 256 * 128;                     // 256*128
    float* EW      = Hc + 256 * 128;                     // 16384*128

    k_pre<<<1152, 256, 0, stream>>>(nodes, W_en, b_en, edges, W_r1,
                                    hA, rowcnt, rowlist, EW);

    k_iter<<<1024, 256, 0, stream>>>(edges, W_agg, b_agg, hA, rowcnt, rowlist, agg);
    k_gru<<<256, 256, 0, stream>>>(agg, W_ih, W_hh, b_ih, b_hh, hA, hB,
                                   W_r1, b_r1, Ha, Hc, 0);
    k_iter<<<1024, 256, 0, stream>>>(edges, W_agg, b_agg, hB, rowcnt, rowlist, agg);
    k_gru<<<256, 256, 0, stream>>>(agg, W_ih, W_hh, b_ih, b_hh, hB, hA,
                                   W_r1, b_r1, Ha, Hc, 0);
    k_iter<<<1024, 256, 0, stream>>>(edges, W_agg, b_agg, hA, rowcnt, rowlist, agg);
    k_gru<<<256, 256, 0, stream>>>(agg, W_ih, W_hh, b_ih, b_hh, hA, hB,
                                   W_r1, b_r1, Ha, Hc, 1);

    k_readout<<<256, 512, 0, stream>>>(EW, Ha, Hc, W_r2, b_r2, W_r3, b_r3,
                                       (float*)d_out);
}